// Round 10
// baseline (546.633 us; speedup 1.0000x reference)
//
#include <hip/hip_runtime.h>
#include <math.h>

#define B_ 16
#define H_ 224
#define W_ 224
#define HP_ 226
#define WP_ 226
#define NPIX_ (B_ * H_ * W_)      /* 802816 */
#define NPAD_ (B_ * HP_ * WP_)    /* 817216 */
#define NROWS_ (B_ * H_ * 2)      /* 7168 half-rows (112 px each) */
#define NBLKC_ (NROWS_ / 4)       /* 1792 blocks, 4 waves/block */
#define MAXNORM_ 0.999f
#define MINN_ 1e-7f
#define TCL_ (1.0f - 1e-5f)
#define LCLAMP_ 3.8002012f        /* atanh(0.999) */
#define BN_EPS_ 1e-5f
#define NF_ ((float)NPIX_)

// ---------------------------------------------------------------------------
// R10. R9 (lane=channel + shfl_xor butterflies) profiled at k3=264us with
// VALU issue saturated and WRITE_SIZE clean: the conv/store dataflow is
// right, but each __shfl_xor is a DS-pipe op (~6cyc, one DS unit per CU);
// 18 shfl/px x 28 waves/CU x 112 px = ~141us of DS serialization. Fix:
//  (1) reductions via DPP (v_add_f32_dpp row_shr/row_bcast, VALU pipe,
//      zero DS) + v_readlane(63) broadcast;
//  (2) no LDS staging at all: window columns read from u0p at wave-uniform
//      addresses (wid via readfirstlane -> scalar s_load path);
//  (3) 4-slot rotating register window (no per-pixel register copies).
// ---------------------------------------------------------------------------

// ---------------------------------------------------------------------------
// K0: x (NCHW f32) -> u0p (padded NHWC4): u0 = logmap0(projx(x)) per pixel,
// zero halo ring. atanh(t) = 0.5*log((1+t)/(1-t)) via v_log_f32.
// ---------------------------------------------------------------------------
__global__ void k0_transform(const float* __restrict__ x, float4* __restrict__ u0p) {
  int idx = blockIdx.x * 256 + threadIdx.x;
  if (idx >= NPAD_) return;
  int b = idx / (HP_ * WP_);
  int r = idx % (HP_ * WP_);
  int yp = r / WP_, xp = r % WP_;
  float4 o = make_float4(0.f, 0.f, 0.f, 0.f);
  if (yp >= 1 && yp <= H_ && xp >= 1 && xp <= W_) {
    const float* xb = x + (size_t)b * (3 * H_ * W_) + (size_t)(yp - 1) * W_ + (xp - 1);
    float v0 = xb[0];
    float v1 = xb[H_ * W_];
    float v2 = xb[2 * H_ * W_];
    // projx
    float n = sqrtf(fmaf(v0, v0, fmaf(v1, v1, v2 * v2)));
    float ncl = fmaxf(n, MINN_);
    float s = fminf(1.0f, MAXNORM_ / ncl);
    float p0 = v0 * s, p1 = v1 * s, p2 = v2 * s;
    // logmap0
    float np_ = fmaxf(sqrtf(fmaf(p0, p0, fmaf(p1, p1, p2 * p2))), MINN_);
    float t = fminf(np_, TCL_);
    float ath = 0.5f * __logf(__fdividef(1.0f + t, 1.0f - t));
    float f = __fdividef(ath, np_);
    o.x = p0 * f; o.y = p1 * f; o.z = p2 * f;
  }
  u0p[idx] = o;
}

// ---------------------------------------------------------------------------
// DPP wave64 sum: row_shr 1/2/4/8 accumulate row sums into lane15 of each
// 16-lane row; row_bcast:15 (rows 1,3) then row_bcast:31 (rows 2,3) roll the
// rows up so lane 63 holds the full 64-lane total; readlane(63) broadcasts
// it via SGPR. old=0 + bound_ctrl means masked/invalid lanes contribute 0,
// which lets GCNDPPCombine fold mov_dpp+add into v_add_f32_dpp (VALU pipe,
// no DS). Requires full exec (all code below is divergence-free).
// ---------------------------------------------------------------------------
__device__ __forceinline__ float dpp_sum64(float x) {
#define DPPA_(ctrl, rmask)                                                   \
  x += __int_as_float(__builtin_amdgcn_update_dpp(                           \
      0, __float_as_int(x), (ctrl), (rmask), 0xf, true));
  DPPA_(0x111, 0xf)  // row_shr:1
  DPPA_(0x112, 0xf)  // row_shr:2
  DPPA_(0x114, 0xf)  // row_shr:4
  DPPA_(0x118, 0xf)  // row_shr:8
  DPPA_(0x142, 0xa)  // row_bcast:15 -> rows 1,3
  DPPA_(0x143, 0xc)  // row_bcast:31 -> rows 2,3
#undef DPPA_
  return __int_as_float(__builtin_amdgcn_readlane(__float_as_int(x), 63));
}

// ---- conv machinery (lane = channel) --------------------------------------
// column slot: 3 float4 (padded rows y, y+1, y+2)
#define DEFCOL(n) float4 n##0, n##1, n##2;
// load padded column cp (relative to ubase) straight from global at a
// wave-uniform address -> scalar-load path, no LDS, no DS ops.
#define LDCOLG(n, cp) {                                                      \
  n##0 = ubase[(cp)];                                                        \
  n##1 = ubase[WP_ + (cp)];                                                  \
  n##2 = ubase[2 * WP_ + (cp)]; }

// accumulate kernel-column d (rows 0..2, cin 0..2) of window column X
// w_[k], k = (ky*3+kx)*3+ci  (HWIO: wgt[k*64 + lane]); all indices constant.
#define C3(acc, X, d)                                                        \
  acc = fmaf((X##0).x, w_[((0 * 3 + (d)) * 3) + 0], acc);                    \
  acc = fmaf((X##0).y, w_[((0 * 3 + (d)) * 3) + 1], acc);                    \
  acc = fmaf((X##0).z, w_[((0 * 3 + (d)) * 3) + 2], acc);                    \
  acc = fmaf((X##1).x, w_[((1 * 3 + (d)) * 3) + 0], acc);                    \
  acc = fmaf((X##1).y, w_[((1 * 3 + (d)) * 3) + 1], acc);                    \
  acc = fmaf((X##1).z, w_[((1 * 3 + (d)) * 3) + 2], acc);                    \
  acc = fmaf((X##2).x, w_[((2 * 3 + (d)) * 3) + 0], acc);                    \
  acc = fmaf((X##2).y, w_[((2 * 3 + (d)) * 3) + 1], acc);                    \
  acc = fmaf((X##2).z, w_[((2 * 3 + (d)) * 3) + 2], acc);

// wave/role setup shared by k1/k3: wave = half-row (112 px). wid is forced
// wave-uniform via readfirstlane so ubase is provably uniform -> s_load.
#define CONV_SETUP()                                                         \
  int tid = threadIdx.x, lane = tid & 63;                                    \
  int wid = __builtin_amdgcn_readfirstlane(tid >> 6);                        \
  int id = blockIdx.x * 4 + wid;                                             \
  int b = id / (H_ * 2); int rem = id % (H_ * 2);                            \
  int y = rem >> 1; int hx0 = (rem & 1) * 112;                               \
  float w_[27];                                                              \
  _Pragma("unroll")                                                          \
  for (int k = 0; k < 27; k++) w_[k] = wgt[k * 64 + lane];                   \
  float bi = bias[lane];                                                     \
  const float4* ubase = u0p + ((size_t)b * HP_ + y) * WP_ + hx0;

// ---------------------------------------------------------------------------
// K1: conv + clamp + BN statistics. Per pixel: 27 FMA + 1 DPP-sum (6 VALU)
// + ~8 scalar-tail VALU + 2 stat FMAs. Lane c holds channel c's (sum, sumsq)
// for its half-row; one coalesced 128-float store per wave at the end.
// ---------------------------------------------------------------------------
__global__ void __launch_bounds__(256, 4)
k1_stats(const float4* __restrict__ u0p, const float* __restrict__ wgt,
         const float* __restrict__ bias, float* __restrict__ partials) {
  CONV_SETUP()
  float s = 0.f, q = 0.f;

#define K1PX(A, B, C) {                                                      \
    float acc = bi; C3(acc, A, 0) C3(acc, B, 1) C3(acc, C, 2)                \
    float n2 = dpp_sum64(acc * acc);                                         \
    float n = sqrtf(n2);                                                     \
    float sc = (n > LCLAMP_) ? __fdividef(LCLAMP_, n) : 1.0f;                \
    float tt = acc * sc;                                                     \
    s += tt; q = fmaf(tt, tt, q); }

  DEFCOL(S0) DEFCOL(S1) DEFCOL(S2) DEFCOL(S3)
  LDCOLG(S0, 0) LDCOLG(S1, 1) LDCOLG(S2, 2)
  for (int g4 = 0; g4 < 27; ++g4) {
    int px = g4 * 4;
    { LDCOLG(S3, px + 3) K1PX(S0, S1, S2) }
    { LDCOLG(S0, px + 4) K1PX(S1, S2, S3) }
    { LDCOLG(S1, px + 5) K1PX(S2, S3, S0) }
    { LDCOLG(S2, px + 6) K1PX(S3, S0, S1) }
  }
  // tail px = 108..111 (cols 111..113 still exist; col 114 does not)
  { LDCOLG(S3, 111) K1PX(S0, S1, S2) }
  { LDCOLG(S0, 112) K1PX(S1, S2, S3) }
  { LDCOLG(S1, 113) K1PX(S2, S3, S0) }
  { K1PX(S3, S0, S1) }
#undef K1PX

  partials[(size_t)id * 128 + lane] = s;
  partials[(size_t)id * 128 + 64 + lane] = q;
}

// ---------------------------------------------------------------------------
// K2: 64 blocks, one per channel. Block c reduces the sum and sumsq columns
// of partials[7168][128] and writes mean[c], rstd*gamma[c].
// ---------------------------------------------------------------------------
__global__ void k2_finalize(const float* __restrict__ partials, const float* __restrict__ gamma,
                            float* __restrict__ stats) {
  int c = blockIdx.x;      // 0..63
  int t = threadIdx.x;     // 256 threads
  float s = 0.f, q = 0.f;
  for (int i = t; i < NROWS_; i += 256) {
    s += partials[(size_t)i * 128 + c];
    q += partials[(size_t)i * 128 + 64 + c];
  }
  __shared__ float ls[256], lq[256];
  ls[t] = s; lq[t] = q;
  __syncthreads();
#pragma unroll
  for (int off = 128; off > 0; off >>= 1) {
    if (t < off) { ls[t] += ls[t + off]; lq[t] += lq[t + off]; }
    __syncthreads();
  }
  if (t == 0) {
    float mean = ls[0] / NF_;
    float msq  = lq[0] / NF_;
    float var = msq - mean * mean;            // jnp.var (ddof=0)
    stats[c] = mean;
    stats[64 + c] = gamma[c] / sqrtf(var + BN_EPS_);
  }
}

// ---------------------------------------------------------------------------
// K3: conv + clamp + BN + relu + expmap0(+projx) + store. Per pixel: 27 FMA,
// 3 DPP-sums (clamp norm, post-BN norm, post-relu norm), per-pixel scalar
// tail on all lanes, then out[px*64 + lane] = g*relu(u3): one contiguous
// 256B store per pixel (2 full cache lines, zero write amplification).
// ---------------------------------------------------------------------------
__global__ void __launch_bounds__(256, 4)
k3_final(const float4* __restrict__ u0p, const float* __restrict__ wgt,
         const float* __restrict__ bias, const float* __restrict__ stats,
         const float* __restrict__ beta, float* __restrict__ out) {
  CONV_SETUP()
  float mn = stats[lane], rgv = stats[64 + lane];
  float bt = beta[lane];
  float* obase = out + ((size_t)((b * H_ + y) * W_) + hx0) * 64;

#define K3PX(A, B, C, px) {                                                  \
    float acc = bi; C3(acc, A, 0) C3(acc, B, 1) C3(acc, C, 2)                \
    float n2 = dpp_sum64(acc * acc);                                         \
    float n = sqrtf(n2);                                                     \
    float sc = (n > LCLAMP_) ? __fdividef(LCLAMP_, n) : 1.0f;                \
    float u3 = (acc * sc - mn) * rgv + bt;                                   \
    float rl = fmaxf(u3, 0.f);                                               \
    float a2 = dpp_sum64(u3 * u3);                                           \
    float r2 = dpp_sum64(rl * rl);                                           \
    float nv = sqrtf(a2);                                                    \
    float sv = (nv > LCLAMP_) ? __fdividef(LCLAMP_, nv) : 1.0f;              \
    float nw = fmaxf(sv * sqrtf(r2), MINN_);                                 \
    float e2 = __expf(2.0f * nw);                                            \
    float th = 1.0f - __fdividef(2.0f, e2 + 1.0f);                           \
    float se = __fdividef(th, nw);                                           \
    float clip = fminf(1.0f, MAXNORM_ / fmaxf(th, MINN_));                   \
    float g = se * clip * sv;                                                \
    obase[(size_t)(px) * 64 + lane] = rl * g; }

  DEFCOL(S0) DEFCOL(S1) DEFCOL(S2) DEFCOL(S3)
  LDCOLG(S0, 0) LDCOLG(S1, 1) LDCOLG(S2, 2)
  for (int g4 = 0; g4 < 27; ++g4) {
    int px = g4 * 4;
    { LDCOLG(S3, px + 3) K3PX(S0, S1, S2, px + 0) }
    { LDCOLG(S0, px + 4) K3PX(S1, S2, S3, px + 1) }
    { LDCOLG(S1, px + 5) K3PX(S2, S3, S0, px + 2) }
    { LDCOLG(S2, px + 6) K3PX(S3, S0, S1, px + 3) }
  }
  // tail px = 108..111
  { LDCOLG(S3, 111) K3PX(S0, S1, S2, 108) }
  { LDCOLG(S0, 112) K3PX(S1, S2, S3, 109) }
  { LDCOLG(S1, 113) K3PX(S2, S3, S0, 110) }
  { K3PX(S3, S0, S1, 111) }
#undef K3PX
}

// ---------------------------------------------------------------------------
extern "C" void kernel_launch(void* const* d_in, const int* in_sizes, int n_in,
                              void* d_out, int out_size, void* d_ws, size_t ws_size,
                              hipStream_t stream) {
  const float* x     = (const float*)d_in[0];  // [16,3,224,224]
  const float* wgt   = (const float*)d_in[1];  // [3,3,3,64] HWIO
  const float* bias  = (const float*)d_in[2];  // [64]
  const float* gamma = (const float*)d_in[3];  // [64]
  const float* beta  = (const float*)d_in[4];  // [64]
  float* out = (float*)d_out;                  // [16,224,224,64]

  char* ws = (char*)d_ws;
  float4* u0p      = (float4*)ws;                                           // 13,075,456 B
  float*  partials = (float*)(ws + (size_t)NPAD_ * 16);                     //  3,670,016 B
  float*  stats    = (float*)(ws + (size_t)NPAD_ * 16 + (size_t)NROWS_ * 128 * 4); // 512 B

  hipLaunchKernelGGL(k0_transform, dim3((NPAD_ + 255) / 256), dim3(256), 0, stream, x, u0p);
  hipLaunchKernelGGL(k1_stats,     dim3(NBLKC_),              dim3(256), 0, stream, u0p, wgt, bias, partials);
  hipLaunchKernelGGL(k2_finalize,  dim3(64),                  dim3(256), 0, stream, partials, gamma, stats);
  hipLaunchKernelGGL(k3_final,     dim3(NBLKC_),              dim3(256), 0, stream, u0p, wgt, bias, stats, beta, out);
}

// Round 12
// 545.276 us; speedup vs baseline: 1.0025x; 1.0025x over previous
//
#include <hip/hip_runtime.h>
#include <math.h>

#define B_ 16
#define H_ 224
#define W_ 224
#define HP_ 226
#define WP_ 226
#define NPIX_ (B_ * H_ * W_)      /* 802816 */
#define NPAD_ (B_ * HP_ * WP_)    /* 817216 */
#define NROWS_ (B_ * H_ * 2)      /* 7168 half-rows (112 px each) */
#define NBLKC_ (NROWS_ / 4)       /* 1792 blocks, 4 waves/block */
#define MAXNORM_ 0.999f
#define MINN_ 1e-7f
#define TCL_ (1.0f - 1e-5f)
#define LCLAMP_ 3.8002012f        /* atanh(0.999) */
#define BN_EPS_ 1e-5f
#define NF_ ((float)NPIX_)

// ---------------------------------------------------------------------------
// R12 = R11 resubmitted verbatim (R11 bench was a GPUAcquisitionTimeout).
// R9/R10 (lane=channel) were measured with VGPR_Count=32 -- impossible
// for 27 resident weights + window + accs. Root cause: `float w_[27]` filled
// by a loop-indexed store hits the SROA-before-unroll alloca trap (documented
// in this kernel's own R0 header): the array stays in scratch and every
// weight read per pixel is a scratch VMEM load (~415 instr-equivalents/px
// measured vs ~70 expected; derived VALUBusy pegged >100%, unreliable).
// Fix (ONLY change vs R10): weights as 27 NAMED scalars w0..w26 loaded by
// macro-expanded constant statements; C3 split into C3A/C3B/C3C with names
// hard-coded. DPP reductions, SGPR window, rotating slots unchanged.
// ---------------------------------------------------------------------------

// ---------------------------------------------------------------------------
// K0: x (NCHW f32) -> u0p (padded NHWC4): u0 = logmap0(projx(x)) per pixel,
// zero halo ring. atanh(t) = 0.5*log((1+t)/(1-t)) via v_log_f32.
// ---------------------------------------------------------------------------
__global__ void k0_transform(const float* __restrict__ x, float4* __restrict__ u0p) {
  int idx = blockIdx.x * 256 + threadIdx.x;
  if (idx >= NPAD_) return;
  int b = idx / (HP_ * WP_);
  int r = idx % (HP_ * WP_);
  int yp = r / WP_, xp = r % WP_;
  float4 o = make_float4(0.f, 0.f, 0.f, 0.f);
  if (yp >= 1 && yp <= H_ && xp >= 1 && xp <= W_) {
    const float* xb = x + (size_t)b * (3 * H_ * W_) + (size_t)(yp - 1) * W_ + (xp - 1);
    float v0 = xb[0];
    float v1 = xb[H_ * W_];
    float v2 = xb[2 * H_ * W_];
    // projx
    float n = sqrtf(fmaf(v0, v0, fmaf(v1, v1, v2 * v2)));
    float ncl = fmaxf(n, MINN_);
    float s = fminf(1.0f, MAXNORM_ / ncl);
    float p0 = v0 * s, p1 = v1 * s, p2 = v2 * s;
    // logmap0
    float np_ = fmaxf(sqrtf(fmaf(p0, p0, fmaf(p1, p1, p2 * p2))), MINN_);
    float t = fminf(np_, TCL_);
    float ath = 0.5f * __logf(__fdividef(1.0f + t, 1.0f - t));
    float f = __fdividef(ath, np_);
    o.x = p0 * f; o.y = p1 * f; o.z = p2 * f;
  }
  u0p[idx] = o;
}

// ---------------------------------------------------------------------------
// DPP wave64 sum: row_shr 1/2/4/8 accumulate row sums into lane15 of each
// 16-lane row; row_bcast:15 (rows 1,3) then row_bcast:31 (rows 2,3) roll the
// rows up so lane 63 holds the full 64-lane total; readlane(63) broadcasts
// it via SGPR. Verified correct in R10 (passed, same absmax).
// ---------------------------------------------------------------------------
__device__ __forceinline__ float dpp_sum64(float x) {
#define DPPA_(ctrl, rmask)                                                   \
  x += __int_as_float(__builtin_amdgcn_update_dpp(                           \
      0, __float_as_int(x), (ctrl), (rmask), 0xf, true));
  DPPA_(0x111, 0xf)  // row_shr:1
  DPPA_(0x112, 0xf)  // row_shr:2
  DPPA_(0x114, 0xf)  // row_shr:4
  DPPA_(0x118, 0xf)  // row_shr:8
  DPPA_(0x142, 0xa)  // row_bcast:15 -> rows 1,3
  DPPA_(0x143, 0xc)  // row_bcast:31 -> rows 2,3
#undef DPPA_
  return __int_as_float(__builtin_amdgcn_readlane(__float_as_int(x), 63));
}

// ---- conv machinery (lane = channel) --------------------------------------
// column slot: 3 float4 (padded rows y, y+1, y+2)
#define DEFCOL(n) float4 n##0, n##1, n##2;
// load padded column cp (relative to ubase) straight from global at a
// wave-uniform address -> scalar-load path, no LDS, no DS ops.
#define LDCOLG(n, cp) {                                                      \
  n##0 = ubase[(cp)];                                                        \
  n##1 = ubase[WP_ + (cp)];                                                  \
  n##2 = ubase[2 * WP_ + (cp)]; }

// Weight name k = (ky*3+kx)*3+ci (HWIO: wgt[k*64 + lane]). 27 NAMED scalars:
#define EACHW(X) X(0) X(1) X(2) X(3) X(4) X(5) X(6) X(7) X(8) X(9) X(10)     \
                 X(11) X(12) X(13) X(14) X(15) X(16) X(17) X(18) X(19)       \
                 X(20) X(21) X(22) X(23) X(24) X(25) X(26)
#define DECLW(k) float w##k = wgt[(k) * 64 + lane];

// kernel-column d of window column X, weight names hard-coded per d:
// d=0: ky0 ci0..2 = w0,w1,w2 ; ky1 = w9,w10,w11 ; ky2 = w18,w19,w20
#define C3A(acc, X)                                                          \
  acc = fmaf((X##0).x, w0, acc);  acc = fmaf((X##0).y, w1, acc);             \
  acc = fmaf((X##0).z, w2, acc);                                             \
  acc = fmaf((X##1).x, w9, acc);  acc = fmaf((X##1).y, w10, acc);            \
  acc = fmaf((X##1).z, w11, acc);                                            \
  acc = fmaf((X##2).x, w18, acc); acc = fmaf((X##2).y, w19, acc);            \
  acc = fmaf((X##2).z, w20, acc);
// d=1: w3,w4,w5 ; w12,w13,w14 ; w21,w22,w23
#define C3B(acc, X)                                                          \
  acc = fmaf((X##0).x, w3, acc);  acc = fmaf((X##0).y, w4, acc);             \
  acc = fmaf((X##0).z, w5, acc);                                             \
  acc = fmaf((X##1).x, w12, acc); acc = fmaf((X##1).y, w13, acc);            \
  acc = fmaf((X##1).z, w14, acc);                                            \
  acc = fmaf((X##2).x, w21, acc); acc = fmaf((X##2).y, w22, acc);            \
  acc = fmaf((X##2).z, w23, acc);
// d=2: w6,w7,w8 ; w15,w16,w17 ; w24,w25,w26
#define C3C(acc, X)                                                          \
  acc = fmaf((X##0).x, w6, acc);  acc = fmaf((X##0).y, w7, acc);             \
  acc = fmaf((X##0).z, w8, acc);                                             \
  acc = fmaf((X##1).x, w15, acc); acc = fmaf((X##1).y, w16, acc);            \
  acc = fmaf((X##1).z, w17, acc);                                            \
  acc = fmaf((X##2).x, w24, acc); acc = fmaf((X##2).y, w25, acc);            \
  acc = fmaf((X##2).z, w26, acc);

// wave/role setup shared by k1/k3: wave = half-row (112 px). wid is forced
// wave-uniform via readfirstlane so ubase is provably uniform -> s_load.
#define CONV_SETUP()                                                         \
  int tid = threadIdx.x, lane = tid & 63;                                    \
  int wid = __builtin_amdgcn_readfirstlane(tid >> 6);                        \
  int id = blockIdx.x * 4 + wid;                                             \
  int b = id / (H_ * 2); int rem = id % (H_ * 2);                            \
  int y = rem >> 1; int hx0 = (rem & 1) * 112;                               \
  EACHW(DECLW)                                                               \
  float bi = bias[lane];                                                     \
  const float4* ubase = u0p + ((size_t)b * HP_ + y) * WP_ + hx0;

// ---------------------------------------------------------------------------
// K1: conv + clamp + BN statistics. Per pixel: 27 FMA + 1 DPP-sum + scalar
// tail + 2 stat FMAs. Lane c holds channel c's (sum, sumsq) for its
// half-row; one coalesced 128-float store per wave at the end.
// ---------------------------------------------------------------------------
__global__ void __launch_bounds__(256, 4)
k1_stats(const float4* __restrict__ u0p, const float* __restrict__ wgt,
         const float* __restrict__ bias, float* __restrict__ partials) {
  CONV_SETUP()
  float s = 0.f, q = 0.f;

#define K1PX(A, B, C) {                                                      \
    float acc = bi; C3A(acc, A) C3B(acc, B) C3C(acc, C)                      \
    float n2 = dpp_sum64(acc * acc);                                         \
    float n = sqrtf(n2);                                                     \
    float sc = (n > LCLAMP_) ? __fdividef(LCLAMP_, n) : 1.0f;                \
    float tt = acc * sc;                                                     \
    s += tt; q = fmaf(tt, tt, q); }

  DEFCOL(S0) DEFCOL(S1) DEFCOL(S2) DEFCOL(S3)
  LDCOLG(S0, 0) LDCOLG(S1, 1) LDCOLG(S2, 2)
  for (int g4 = 0; g4 < 27; ++g4) {
    int px = g4 * 4;
    { LDCOLG(S3, px + 3) K1PX(S0, S1, S2) }
    { LDCOLG(S0, px + 4) K1PX(S1, S2, S3) }
    { LDCOLG(S1, px + 5) K1PX(S2, S3, S0) }
    { LDCOLG(S2, px + 6) K1PX(S3, S0, S1) }
  }
  // tail px = 108..111 (cols 111..113 still exist; col 114 does not)
  { LDCOLG(S3, 111) K1PX(S0, S1, S2) }
  { LDCOLG(S0, 112) K1PX(S1, S2, S3) }
  { LDCOLG(S1, 113) K1PX(S2, S3, S0) }
  { K1PX(S3, S0, S1) }
#undef K1PX

  partials[(size_t)id * 128 + lane] = s;
  partials[(size_t)id * 128 + 64 + lane] = q;
}

// ---------------------------------------------------------------------------
// K2: 64 blocks, one per channel. Block c reduces the sum and sumsq columns
// of partials[7168][128] and writes mean[c], rstd*gamma[c].
// ---------------------------------------------------------------------------
__global__ void k2_finalize(const float* __restrict__ partials, const float* __restrict__ gamma,
                            float* __restrict__ stats) {
  int c = blockIdx.x;      // 0..63
  int t = threadIdx.x;     // 256 threads
  float s = 0.f, q = 0.f;
  for (int i = t; i < NROWS_; i += 256) {
    s += partials[(size_t)i * 128 + c];
    q += partials[(size_t)i * 128 + 64 + c];
  }
  __shared__ float ls[256], lq[256];
  ls[t] = s; lq[t] = q;
  __syncthreads();
#pragma unroll
  for (int off = 128; off > 0; off >>= 1) {
    if (t < off) { ls[t] += ls[t + off]; lq[t] += lq[t + off]; }
    __syncthreads();
  }
  if (t == 0) {
    float mean = ls[0] / NF_;
    float msq  = lq[0] / NF_;
    float var = msq - mean * mean;            // jnp.var (ddof=0)
    stats[c] = mean;
    stats[64 + c] = gamma[c] / sqrtf(var + BN_EPS_);
  }
}

// ---------------------------------------------------------------------------
// K3: conv + clamp + BN + relu + expmap0(+projx) + store. Per pixel: 27 FMA,
// 3 DPP-sums (clamp norm, post-BN norm, post-relu norm), per-pixel scalar
// tail on all lanes, then out[px*64 + lane] = g*relu(u3): one contiguous
// 256B store per pixel (2 full cache lines, zero write amplification).
// ---------------------------------------------------------------------------
__global__ void __launch_bounds__(256, 4)
k3_final(const float4* __restrict__ u0p, const float* __restrict__ wgt,
         const float* __restrict__ bias, const float* __restrict__ stats,
         const float* __restrict__ beta, float* __restrict__ out) {
  CONV_SETUP()
  float mn = stats[lane], rgv = stats[64 + lane];
  float bt = beta[lane];
  float* obase = out + ((size_t)((b * H_ + y) * W_) + hx0) * 64;

#define K3PX(A, B, C, px) {                                                  \
    float acc = bi; C3A(acc, A) C3B(acc, B) C3C(acc, C)                      \
    float n2 = dpp_sum64(acc * acc);                                         \
    float n = sqrtf(n2);                                                     \
    float sc = (n > LCLAMP_) ? __fdividef(LCLAMP_, n) : 1.0f;                \
    float u3 = (acc * sc - mn) * rgv + bt;                                   \
    float rl = fmaxf(u3, 0.f);                                               \
    float a2 = dpp_sum64(u3 * u3);                                           \
    float r2 = dpp_sum64(rl * rl);                                           \
    float nv = sqrtf(a2);                                                    \
    float sv = (nv > LCLAMP_) ? __fdividef(LCLAMP_, nv) : 1.0f;              \
    float nw = fmaxf(sv * sqrtf(r2), MINN_);                                 \
    float e2 = __expf(2.0f * nw);                                            \
    float th = 1.0f - __fdividef(2.0f, e2 + 1.0f);                           \
    float se = __fdividef(th, nw);                                           \
    float clip = fminf(1.0f, MAXNORM_ / fmaxf(th, MINN_));                   \
    float g = se * clip * sv;                                                \
    obase[(size_t)(px) * 64 + lane] = rl * g; }

  DEFCOL(S0) DEFCOL(S1) DEFCOL(S2) DEFCOL(S3)
  LDCOLG(S0, 0) LDCOLG(S1, 1) LDCOLG(S2, 2)
  for (int g4 = 0; g4 < 27; ++g4) {
    int px = g4 * 4;
    { LDCOLG(S3, px + 3) K3PX(S0, S1, S2, px + 0) }
    { LDCOLG(S0, px + 4) K3PX(S1, S2, S3, px + 1) }
    { LDCOLG(S1, px + 5) K3PX(S2, S3, S0, px + 2) }
    { LDCOLG(S2, px + 6) K3PX(S3, S0, S1, px + 3) }
  }
  // tail px = 108..111
  { LDCOLG(S3, 111) K3PX(S0, S1, S2, 108) }
  { LDCOLG(S0, 112) K3PX(S1, S2, S3, 109) }
  { LDCOLG(S1, 113) K3PX(S2, S3, S0, 110) }
  { K3PX(S3, S0, S1, 111) }
#undef K3PX
}

// ---------------------------------------------------------------------------
extern "C" void kernel_launch(void* const* d_in, const int* in_sizes, int n_in,
                              void* d_out, int out_size, void* d_ws, size_t ws_size,
                              hipStream_t stream) {
  const float* x     = (const float*)d_in[0];  // [16,3,224,224]
  const float* wgt   = (const float*)d_in[1];  // [3,3,3,64] HWIO
  const float* bias  = (const float*)d_in[2];  // [64]
  const float* gamma = (const float*)d_in[3];  // [64]
  const float* beta  = (const float*)d_in[4];  // [64]
  float* out = (float*)d_out;                  // [16,224,224,64]

  char* ws = (char*)d_ws;
  float4* u0p      = (float4*)ws;                                           // 13,075,456 B
  float*  partials = (float*)(ws + (size_t)NPAD_ * 16);                     //  3,670,016 B
  float*  stats    = (float*)(ws + (size_t)NPAD_ * 16 + (size_t)NROWS_ * 128 * 4); // 512 B

  hipLaunchKernelGGL(k0_transform, dim3((NPAD_ + 255) / 256), dim3(256), 0, stream, x, u0p);
  hipLaunchKernelGGL(k1_stats,     dim3(NBLKC_),              dim3(256), 0, stream, u0p, wgt, bias, partials);
  hipLaunchKernelGGL(k2_finalize,  dim3(64),                  dim3(256), 0, stream, partials, gamma, stats);
  hipLaunchKernelGGL(k3_final,     dim3(NBLKC_),              dim3(256), 0, stream, u0p, wgt, bias, stats, beta, out);
}

// Round 13
// 306.642 us; speedup vs baseline: 1.7826x; 1.7782x over previous
//
#include <hip/hip_runtime.h>
#include <math.h>

#define B_ 16
#define H_ 224
#define W_ 224
#define HP_ 226
#define WP_ 226
#define CIN_ 3
#define COUT_ 64
#define NPIX_ (B_ * H_ * W_)      /* 802816 */
#define NPAD_ (B_ * HP_ * WP_)    /* 817216 */
#define NBLK_ (NPIX_ / 256)       /* 3136 */
#define MAXNORM_ 0.999f
#define MINN_ 1e-7f
#define TCL_ (1.0f - 1e-5f)
#define LCLAMP_ 3.8002012f        /* atanh(0.999) */
#define BN_EPS_ 1e-5f
#define NF_ ((float)NPIX_)
#define PADW2_ 36

typedef float v4f __attribute__((ext_vector_type(4)));

// ---------------------------------------------------------------------------
// R13 = R4's proven spill-free half-conv kernel (311us) + ONE change:
// all 9 tap loads hoisted into named float4 registers BEFORE any FMA and
// reused across both 32-channel halves, pinned with sched_barrier(0).
// Why: mapping-A's weights are wave-uniform -> scalar pipe (s_load, free;
// explains R5's regression when they were moved to LDS/DS pipe). The 80%
// stall (VALUBusy 20%) is the 9 load-then-use tap batches: u0p (13MB) misses
// the 4MB per-XCD L2 (rows re-read by 3 block-rows on different XCDs), so
// each of 9(x2 halves) serialized waitcnts costs ~600cyc vs ~1700 issue
// cycles/wave. Hoisting = ONE wait, and halves the tap-load count.
// ---------------------------------------------------------------------------
struct Acc8 { v4f v0, v1, v2, v3, v4, v5, v6, v7; };
#define EACH8(X) X(0) X(1) X(2) X(3) X(4) X(5) X(6) X(7)

// ---------------------------------------------------------------------------
// K0: x (NCHW f32) -> u0p (padded NHWC4): u0 = logmap0(projx(x)) per pixel,
// zero halo ring. atanh(t) = 0.5*log((1+t)/(1-t)) via v_log_f32.
// ---------------------------------------------------------------------------
__global__ void k0_transform(const float* __restrict__ x, float4* __restrict__ u0p) {
  int idx = blockIdx.x * 256 + threadIdx.x;
  if (idx >= NPAD_) return;
  int b = idx / (HP_ * WP_);
  int r = idx % (HP_ * WP_);
  int yp = r / WP_, xp = r % WP_;
  float4 o = make_float4(0.f, 0.f, 0.f, 0.f);
  if (yp >= 1 && yp <= H_ && xp >= 1 && xp <= W_) {
    const float* xb = x + (size_t)b * (CIN_ * H_ * W_) + (size_t)(yp - 1) * W_ + (xp - 1);
    float v0 = xb[0];
    float v1 = xb[H_ * W_];
    float v2 = xb[2 * H_ * W_];
    // projx
    float n = sqrtf(fmaf(v0, v0, fmaf(v1, v1, v2 * v2)));
    float ncl = fmaxf(n, MINN_);
    float s = fminf(1.0f, MAXNORM_ / ncl);
    float p0 = v0 * s, p1 = v1 * s, p2 = v2 * s;
    // logmap0
    float np_ = fmaxf(sqrtf(fmaf(p0, p0, fmaf(p1, p1, p2 * p2))), MINN_);
    float t = fminf(np_, TCL_);
    float ath = 0.5f * __logf(__fdividef(1.0f + t, 1.0f - t));
    float f = __fdividef(ath, np_);
    o.x = p0 * f; o.y = p1 * f; o.z = p2 * f;
  }
  u0p[idx] = o;
}

// ---- tap hoist: 9 independent global_load_dwordx4, one wait, pinned -------
#define LOADTAPS()                                                           \
  int bb = pix / (H_ * W_);                                                  \
  int rr = pix % (H_ * W_);                                                  \
  int yy = rr / W_, xx = rr % W_;                                            \
  const float4* base = u0p + ((size_t)bb * HP_ + yy) * WP_ + xx;             \
  float4 T0 = base[0],        T1 = base[1],            T2 = base[2];         \
  float4 T3 = base[WP_],      T4 = base[WP_ + 1],      T5 = base[WP_ + 2];   \
  float4 T6 = base[2 * WP_],  T7 = base[2 * WP_ + 1],  T8 = base[2 * WP_ + 2]; \
  __builtin_amdgcn_sched_barrier(0);

// half-conv over hoisted taps: channels [h8*4, h8*4+32) into 8 named v4f.
// Weight addresses are wave-uniform with constant indices -> s_load/SGPR.
#define INIT8(i) a.v##i = b4[h8 + i];
#define FMA_X(i) a.v##i += in.x * wp[h8 + i];
#define FMA_Y(i) a.v##i += in.y * wp[16 + h8 + i];
#define FMA_Z(i) a.v##i += in.z * wp[32 + h8 + i];
#define TAPF(t, T) { float4 in = T;                                          \
                     const v4f* wp = (const v4f*)(wgt + (t) * 3 * COUT_);    \
                     EACH8(FMA_X) EACH8(FMA_Y) EACH8(FMA_Z) }
#define CONV_HALF(h8v)                                                       \
  { const int h8 = (h8v); const v4f* b4 = (const v4f*)bias;                  \
    EACH8(INIT8)                                                             \
    TAPF(0, T0) TAPF(1, T1) TAPF(2, T2)                                      \
    TAPF(3, T3) TAPF(4, T4) TAPF(5, T5)                                      \
    TAPF(6, T6) TAPF(7, T7) TAPF(8, T8) }

__device__ __forceinline__ v4f vshfl_xor(v4f v, int m) {
  v4f r;
  r.x = __shfl_xor(v.x, m, 64);
  r.y = __shfl_xor(v.y, m, 64);
  r.z = __shfl_xor(v.z, m, 64);
  r.w = __shfl_xor(v.w, m, 64);
  return r;
}
__device__ __forceinline__ v4f vrelu(v4f v) {
  v.x = fmaxf(v.x, 0.f); v.y = fmaxf(v.y, 0.f);
  v.z = fmaxf(v.z, 0.f); v.w = fmaxf(v.w, 0.f);
  return v;
}
__device__ __forceinline__ float hsum(v4f v) { return (v.x + v.y) + (v.z + v.w); }

#define STAGE8() do {                                                        \
  *(v4f*)(row + 0)  = a.v0; *(v4f*)(row + 4)  = a.v1;                        \
  *(v4f*)(row + 8)  = a.v2; *(v4f*)(row + 12) = a.v3;                        \
  *(v4f*)(row + 16) = a.v4; *(v4f*)(row + 20) = a.v5;                        \
  *(v4f*)(row + 24) = a.v6; *(v4f*)(row + 28) = a.v7;                        \
} while (0)

// ---------------------------------------------------------------------------
// K1: conv (two halves over shared hoisted taps) + DEFERRED clamp + stats.
// Stage raw half-A, run half-B in regs, compute per-pixel clamp scale sc,
// publish to LDS, transposed stat read applying sc[row]; repeat for B.
// ---------------------------------------------------------------------------
__global__ void __launch_bounds__(256, 4)
k1_stats(const float4* __restrict__ u0p, const float* __restrict__ wgt,
         const float* __restrict__ bias, float* __restrict__ partials) {
  int pix = blockIdx.x * 256 + threadIdx.x;
  __shared__ __align__(16) float stg[4 * 64 * PADW2_];  // 36,864 B
  __shared__ float scl[256];
  __shared__ float red_s[256], red_q[256];
  int lane = threadIdx.x & 63, wid = threadIdx.x >> 6;
  float* row = stg + (size_t)(wid * 64 + lane) * PADW2_;
  int pr8 = lane >> 3, qi = lane & 7;
  const float* rb = stg + (size_t)wid * 64 * PADW2_ + pr8 * PADW2_ + qi * 4;
  const float* scrow = scl + wid * 64;

  LOADTAPS()
  Acc8 a;
  CONV_HALF(0)
  v4f s2v = (v4f)0.0f;
#define SQ(i) s2v += a.v##i * a.v##i;
  EACH8(SQ)
#undef SQ
  float s2A = hsum(s2v);
  STAGE8();
  __builtin_amdgcn_wave_barrier();

  CONV_HALF(8)                       // half-B lives in regs; taps reused
  s2v = (v4f)0.0f;
#define SQ(i) s2v += a.v##i * a.v##i;
  EACH8(SQ)
#undef SQ
  float n2 = s2A + hsum(s2v);
  float n = sqrtf(n2);
  float sc = (n > LCLAMP_) ? __fdividef(LCLAMP_, n) : 1.0f;
  scl[wid * 64 + lane] = sc;
  __builtin_amdgcn_wave_barrier();

  // transposed stat read of half-A, applying sc[row]
  v4f sA = (v4f)0.0f, qA = (v4f)0.0f;
#pragma unroll
  for (int j = 0; j < 8; j++) {
    float g = scrow[j * 8 + pr8];
    v4f v = *(const v4f*)(rb + j * 8 * PADW2_) * g;
    sA += v; qA += v * v;
  }
  sA += vshfl_xor(sA, 8);  qA += vshfl_xor(qA, 8);
  sA += vshfl_xor(sA, 16); qA += vshfl_xor(qA, 16);
  sA += vshfl_xor(sA, 32); qA += vshfl_xor(qA, 32);
  if (lane < 8) {  // lane qi holds wave-total for ch quad qi (ch 0..31)
    *(v4f*)&red_s[wid * 32 + qi * 4] = sA;
    *(v4f*)&red_q[wid * 32 + qi * 4] = qA;
  }
  __builtin_amdgcn_wave_barrier();

  STAGE8();                          // stage half-B (wave DS ops in order)
  __builtin_amdgcn_wave_barrier();
  v4f sB = (v4f)0.0f, qB = (v4f)0.0f;
#pragma unroll
  for (int j = 0; j < 8; j++) {
    float g = scrow[j * 8 + pr8];
    v4f v = *(const v4f*)(rb + j * 8 * PADW2_) * g;
    sB += v; qB += v * v;
  }
  sB += vshfl_xor(sB, 8);  qB += vshfl_xor(qB, 8);
  sB += vshfl_xor(sB, 16); qB += vshfl_xor(qB, 16);
  sB += vshfl_xor(sB, 32); qB += vshfl_xor(qB, 32);
  if (lane < 8) {
    *(v4f*)&red_s[128 + wid * 32 + qi * 4] = sB;
    *(v4f*)&red_q[128 + wid * 32 + qi * 4] = qB;
  }
  __syncthreads();
  int tid = threadIdx.x;
  if (tid < 128) {
    int c = tid & 63;
    int base2 = (c >> 5) * 128 + (c & 31);
    const float* rr2 = (tid < 64) ? red_s : red_q;
    float tot = rr2[base2] + rr2[base2 + 32] + rr2[base2 + 64] + rr2[base2 + 96];
    // partials[blk*128 + c] = sum_c ; partials[blk*128 + 64 + c] = sumsq_c
    partials[(size_t)blockIdx.x * 128 + tid] = tot;
  }
}

// ---------------------------------------------------------------------------
// K2: 64 blocks, one per channel. Block c reduces the sum and sumsq columns
// of partials[3136][128] and writes mean[c], rstd*gamma[c].
// ---------------------------------------------------------------------------
__global__ void k2_finalize(const float* __restrict__ partials, const float* __restrict__ gamma,
                            float* __restrict__ stats) {
  int c = blockIdx.x;      // 0..63
  int t = threadIdx.x;     // 256 threads
  float s = 0.f, q = 0.f;
  for (int i = t; i < NBLK_; i += 256) {
    s += partials[(size_t)i * 128 + c];
    q += partials[(size_t)i * 128 + 64 + c];
  }
  __shared__ float ls[256], lq[256];
  ls[t] = s; lq[t] = q;
  __syncthreads();
#pragma unroll
  for (int off = 128; off > 0; off >>= 1) {
    if (t < off) { ls[t] += ls[t + off]; lq[t] += lq[t + off]; }
    __syncthreads();
  }
  if (t == 0) {
    float mean = ls[0] / NF_;
    float msq  = lq[0] / NF_;
    float var = msq - mean * mean;            // jnp.var (ddof=0)
    stats[c] = mean;
    stats[64 + c] = gamma[c] / sqrtf(var + BN_EPS_);
  }
}

// ---------------------------------------------------------------------------
// K3: conv (two halves, shared hoisted taps) + BN affine, nonlinear tail
// folded into one per-pixel scalar g = fs*sv (relu(sv*u) = sv*relu(u), sv>0).
// Stage raw BN'd u, publish g, transposed read applies relu + g[row], store
// coalesced (8 x 128B full-sector runs per instruction). tanh via v_exp.
// ---------------------------------------------------------------------------
__global__ void __launch_bounds__(256, 4)
k3_final(const float4* __restrict__ u0p, const float* __restrict__ wgt,
         const float* __restrict__ bias, const float* __restrict__ stats,
         const float* __restrict__ beta, float* __restrict__ out) {
  int pix = blockIdx.x * 256 + threadIdx.x;
  __shared__ __align__(16) float stg[4 * 64 * PADW2_];  // 36,864 B
  __shared__ float gl[256];                             // per-pixel out scale
  int lane = threadIdx.x & 63, wid = threadIdx.x >> 6;
  float* row = stg + (size_t)(wid * 64 + lane) * PADW2_;
  int pr8 = lane >> 3, qi = lane & 7;
  const float* rb = stg + (size_t)wid * 64 * PADW2_ + pr8 * PADW2_ + qi * 4;
  const float* grow = gl + wid * 64;
  v4f* outw = (v4f*)out + ((size_t)blockIdx.x * 256 + wid * 64) * 16;

  const v4f* mean4 = (const v4f*)stats;
  const v4f* rg4   = (const v4f*)(stats + 64);
  const v4f* beta4 = (const v4f*)beta;

  LOADTAPS()
  Acc8 a;
  // ---- half A: conv + BN, accumulate nv2 (pre-relu) and r2 (post-relu) ----
  CONV_HALF(0)
  v4f s2v = (v4f)0.0f, r2v = (v4f)0.0f;
#define BNA(i) { a.v##i = (a.v##i - mean4[i]) * rg4[i] + beta4[i];           \
                 s2v += a.v##i * a.v##i; v4f t_ = vrelu(a.v##i); r2v += t_ * t_; }
  EACH8(BNA)
#undef BNA
  float nv2 = hsum(s2v), r2 = hsum(r2v);
  STAGE8();                          // stage raw BN'd half-A
  __builtin_amdgcn_wave_barrier();

  // ---- half B: conv + BN (stats quads 8..15), finish scalars ----
  CONV_HALF(8)
  s2v = (v4f)0.0f; r2v = (v4f)0.0f;
#define BNB(i) { a.v##i = (a.v##i - mean4[8 + i]) * rg4[8 + i] + beta4[8 + i]; \
                 s2v += a.v##i * a.v##i; v4f t_ = vrelu(a.v##i); r2v += t_ * t_; }
  EACH8(BNB)
#undef BNB
  nv2 += hsum(s2v); r2 += hsum(r2v);
  float nv = sqrtf(nv2);
  float sv = (nv > LCLAMP_) ? __fdividef(LCLAMP_, nv) : 1.0f;  // logmap0∘expmap0
  float nw = fmaxf(sv * sqrtf(r2), MINN_);
  float e2 = __expf(2.0f * nw);                        // tanh via v_exp_f32
  float th = 1.0f - __fdividef(2.0f, e2 + 1.0f);
  float se = __fdividef(th, nw);
  float clip = fminf(1.0f, MAXNORM_ / fmaxf(th, MINN_));
  float g = se * clip * sv;
  gl[wid * 64 + lane] = g;
  __builtin_amdgcn_wave_barrier();

  // ---- store half A: transposed read, relu + g[row], coalesced NT store ----
#pragma unroll
  for (int j = 0; j < 8; j++) {
    float gv = grow[j * 8 + pr8];
    v4f v = vrelu(*(const v4f*)(rb + j * 8 * PADW2_)) * gv;
    __builtin_nontemporal_store(v, outw + (j * 8 + pr8) * 16 + qi);
  }
  __builtin_amdgcn_wave_barrier();

  // ---- stage + store half B (quads 8..15 of each pixel) ----
  STAGE8();
  __builtin_amdgcn_wave_barrier();
#pragma unroll
  for (int j = 0; j < 8; j++) {
    float gv = grow[j * 8 + pr8];
    v4f v = vrelu(*(const v4f*)(rb + j * 8 * PADW2_)) * gv;
    __builtin_nontemporal_store(v, outw + (j * 8 + pr8) * 16 + 8 + qi);
  }
}

// ---------------------------------------------------------------------------
extern "C" void kernel_launch(void* const* d_in, const int* in_sizes, int n_in,
                              void* d_out, int out_size, void* d_ws, size_t ws_size,
                              hipStream_t stream) {
  const float* x     = (const float*)d_in[0];  // [16,3,224,224]
  const float* wgt   = (const float*)d_in[1];  // [3,3,3,64] HWIO
  const float* bias  = (const float*)d_in[2];  // [64]
  const float* gamma = (const float*)d_in[3];  // [64]
  const float* beta  = (const float*)d_in[4];  // [64]
  float* out = (float*)d_out;                  // [16,224,224,64]

  char* ws = (char*)d_ws;
  float4* u0p      = (float4*)ws;                                           // 13,075,456 B
  float*  partials = (float*)(ws + (size_t)NPAD_ * 16);                     //  1,605,632 B
  float*  stats    = (float*)(ws + (size_t)NPAD_ * 16 + (size_t)NBLK_ * 128 * 4); // 512 B

  hipLaunchKernelGGL(k0_transform, dim3((NPAD_ + 255) / 256), dim3(256), 0, stream, x, u0p);
  hipLaunchKernelGGL(k1_stats,     dim3(NBLK_),               dim3(256), 0, stream, u0p, wgt, bias, partials);
  hipLaunchKernelGGL(k2_finalize,  dim3(64),                  dim3(256), 0, stream, partials, gamma, stats);
  hipLaunchKernelGGL(k3_final,     dim3(NBLK_),               dim3(256), 0, stream, u0p, wgt, bias, stats, beta, out);
}